// Round 10
// baseline (118.050 us; speedup 1.0000x reference)
//
#include <hip/hip_runtime.h>

typedef unsigned short u16;
typedef unsigned int u32;
typedef __bf16 bf16x8 __attribute__((ext_vector_type(8)));
typedef float f32x4 __attribute__((ext_vector_type(4)));

#define MFMA16 __builtin_amdgcn_mfma_f32_16x16x32_bf16

__device__ __forceinline__ u16 f2bf(float f) {
    u32 u = __float_as_uint(f);
    u32 r = (u + 0x7fffu + ((u >> 16) & 1u)) >> 16;
    return (u16)r;
}
__device__ __forceinline__ float bf2f(u16 h) {
    return __uint_as_float(((u32)h) << 16);
}
__device__ __forceinline__ bf16x8 ld8(const u16* p) {
    return *reinterpret_cast<const bf16x8*>(p);
}

// ---------------------------------------------------------------------------
// prep: z<2 -> transpose x slice b=z to xT [b][l][c] bf16;
//       z==2 -> convert W's + build emb tables. grid (24,4,3), 256 thr.
// ---------------------------------------------------------------------------
__global__ __launch_bounds__(256) void prep(
    const float* __restrict__ x,
    const float* __restrict__ Wc, const float* __restrict__ Wq,
    const float* __restrict__ Wk, const float* __restrict__ Wf,
    const float* __restrict__ emb,
    u16* __restrict__ xT,
    u16* __restrict__ wcb, u16* __restrict__ wqb, u16* __restrict__ wkb,
    u16* __restrict__ wfb, u16* __restrict__ embR, u16* __restrict__ embT)
{
    const int tid = threadIdx.x;
    const int z = blockIdx.z;
    if (z < 2) {
        __shared__ u16 tile[64][65];
        const int b = z, c0 = blockIdx.y * 64, l0 = blockIdx.x * 64;
        const int cc = tid >> 2, lq = (tid & 3) * 16;
        const float* xp = x + (size_t)((b * 256 + c0 + cc) * 1536 + l0 + lq);
        #pragma unroll
        for (int i = 0; i < 4; ++i) {
            float4 v = *reinterpret_cast<const float4*>(xp + i * 4);
            tile[cc][lq + i * 4 + 0] = f2bf(v.x);
            tile[cc][lq + i * 4 + 1] = f2bf(v.y);
            tile[cc][lq + i * 4 + 2] = f2bf(v.z);
            tile[cc][lq + i * 4 + 3] = f2bf(v.w);
        }
        __syncthreads();
        const int ll = tid >> 2, cq = (tid & 3) * 16;
        u16* op = xT + (size_t)((b * 1536 + l0 + ll) * 256 + c0 + cq);
        #pragma unroll
        for (int i = 0; i < 16; ++i) op[i] = tile[cq + i][ll];
    } else {
        const int idx0 = (blockIdx.y * 24 + blockIdx.x) * 256 + tid;
        for (int i = idx0; i < 65536; i += 24576) {
            wcb[i] = f2bf(Wc[i]); wqb[i] = f2bf(Wq[i]);
            wkb[i] = f2bf(Wk[i]); wfb[i] = f2bf(Wf[i]);
        }
        if (idx0 < 112 * 64) {
            const int j = idx0 >> 6, d = idx0 & 63;
            embR[idx0] = (j < 101) ? f2bf(0.3f * emb[(100 - j) * 64 + d]) : (u16)0;
        }
        if (idx0 < 64 * 128) {
            const int d = idx0 >> 7, j = idx0 & 127;
            embT[idx0] = (j < 101) ? f2bf(0.3f * emb[(100 - j) * 64 + d]) : (u16)0;
        }
    }
}

// ---------------------------------------------------------------------------
// gemm_qkc: fused q/k/content conv1x1, bf16 MFMA, no LDS.
// grid (24, 8, 6), 128 thr = 2 waves; z = which*2 + b.
// ALL operand loads hoisted before MFMAs (cold-cache latency hiding);
// MFMA order identical to round 7/8 -> bit-identical output.
// ---------------------------------------------------------------------------
__global__ __launch_bounds__(128) void gemm_qkc(
    const u16* __restrict__ xT,
    const u16* __restrict__ Wq, const float* __restrict__ bq,
    const u16* __restrict__ Wk, const float* __restrict__ bk,
    const u16* __restrict__ Wc, const float* __restrict__ bc,
    u16* __restrict__ qo, u16* __restrict__ ko, u16* __restrict__ co)
{
    const int tid = threadIdx.x, wv = tid >> 6, lane = tid & 63;
    const int l15 = lane & 15, kg8 = (lane >> 4) * 8;
    const int z = blockIdx.z, b = z & 1, which = z >> 1;
    const u16* W = (which == 0) ? Wq : (which == 1) ? Wk : Wc;
    const float* bias = (which == 0) ? bq : (which == 1) ? bk : bc;
    const int l0 = blockIdx.x * 64 + wv * 32;
    const int ch0 = blockIdx.y * 32;
    const u16* xp = xT + (size_t)(b * 1536 + l0 + l15) * 256 + kg8;
    const u16* wp = W + (size_t)(ch0 + l15) * 256 + kg8;
    const u16* ap = (which == 2) ? wp : xp;
    const u16* bp = (which == 2) ? xp : wp;

    bf16x8 a0r[8], a1r[8], b0r[8], b1r[8];
    #pragma unroll
    for (int kd = 0; kd < 8; ++kd) {
        a0r[kd] = ld8(ap + kd * 32);
        a1r[kd] = ld8(ap + 4096 + kd * 32);
        b0r[kd] = ld8(bp + kd * 32);
        b1r[kd] = ld8(bp + 4096 + kd * 32);
    }
    const f32x4 zf = {0.f, 0.f, 0.f, 0.f};
    f32x4 acc[2][2] = {{zf, zf}, {zf, zf}};
    #pragma unroll
    for (int kd = 0; kd < 8; ++kd) {
        acc[0][0] = MFMA16(a0r[kd], b0r[kd], acc[0][0], 0, 0, 0);
        acc[0][1] = MFMA16(a0r[kd], b1r[kd], acc[0][1], 0, 0, 0);
        acc[1][0] = MFMA16(a1r[kd], b0r[kd], acc[1][0], 0, 0, 0);
        acc[1][1] = MFMA16(a1r[kd], b1r[kd], acc[1][1], 0, 0, 0);
    }
    if (which < 2) {
        u16* outp = which ? ko : qo;
        float bv[2];
        bv[0] = bias[ch0 + l15];
        bv[1] = bias[ch0 + 16 + l15];
        #pragma unroll
        for (int mf = 0; mf < 2; ++mf)
            #pragma unroll
            for (int nf = 0; nf < 2; ++nf)
                #pragma unroll
                for (int r = 0; r < 4; ++r) {
                    const int row = l0 + mf * 16 + (lane >> 4) * 4 + r;
                    outp[(size_t)(b * 1536 + row) * 256 + ch0 + nf * 16 + l15] =
                        f2bf(acc[mf][nf][r] + bv[nf]);
                }
    } else {
        #pragma unroll
        for (int mf = 0; mf < 2; ++mf)
            #pragma unroll
            for (int r = 0; r < 4; ++r) {
                const int ch = ch0 + mf * 16 + (lane >> 4) * 4 + r;
                const float bv = bias[ch];
                #pragma unroll
                for (int nf = 0; nf < 2; ++nf)
                    co[(size_t)(b * 256 + ch) * 1536 + l0 + nf * 16 + l15] =
                        f2bf(acc[mf][nf][r] + bv);
            }
    }
}

// ---------------------------------------------------------------------------
// gemm_f: final conv1x1, bf16 MFMA, loads hoisted. grid (24,8,2), 128 thr
// ---------------------------------------------------------------------------
__global__ __launch_bounds__(128) void gemm_f(
    const u16* __restrict__ W, const float* __restrict__ bias,
    const u16* __restrict__ srcT, u16* __restrict__ outp)
{
    const int tid = threadIdx.x, wv = tid >> 6, lane = tid & 63;
    const int l15 = lane & 15, kg8 = (lane >> 4) * 8;
    const int b = blockIdx.z;
    const int l0 = blockIdx.x * 64 + wv * 32;
    const int ch0 = blockIdx.y * 32;
    const u16* ap = W + (size_t)(ch0 + l15) * 256 + kg8;
    const u16* bp = srcT + (size_t)(b * 1536 + l0 + l15) * 256 + kg8;

    bf16x8 a0r[8], a1r[8], b0r[8], b1r[8];
    #pragma unroll
    for (int kd = 0; kd < 8; ++kd) {
        a0r[kd] = ld8(ap + kd * 32);
        a1r[kd] = ld8(ap + 4096 + kd * 32);
        b0r[kd] = ld8(bp + kd * 32);
        b1r[kd] = ld8(bp + 4096 + kd * 32);
    }
    const f32x4 zf = {0.f, 0.f, 0.f, 0.f};
    f32x4 acc[2][2] = {{zf, zf}, {zf, zf}};
    #pragma unroll
    for (int kd = 0; kd < 8; ++kd) {
        acc[0][0] = MFMA16(a0r[kd], b0r[kd], acc[0][0], 0, 0, 0);
        acc[0][1] = MFMA16(a0r[kd], b1r[kd], acc[0][1], 0, 0, 0);
        acc[1][0] = MFMA16(a1r[kd], b0r[kd], acc[1][0], 0, 0, 0);
        acc[1][1] = MFMA16(a1r[kd], b1r[kd], acc[1][1], 0, 0, 0);
    }
    #pragma unroll
    for (int mf = 0; mf < 2; ++mf)
        #pragma unroll
        for (int r = 0; r < 4; ++r) {
            const int ch = ch0 + mf * 16 + (lane >> 4) * 4 + r;
            const float bv = bias[ch];
            #pragma unroll
            for (int nf = 0; nf < 2; ++nf)
                outp[(size_t)(b * 256 + ch) * 1536 + l0 + nf * 16 + l15] =
                    f2bf(acc[mf][nf][r] + bv);
        }
}

// ---------------------------------------------------------------------------
// attn_mfma: K-gather loads hoisted before QK MFMAs; otherwise identical.
// grid (48, 8), 128 thr = 2 waves.
// ---------------------------------------------------------------------------
#define WST 168
#define WBST 136
#define BST 114

__global__ __launch_bounds__(128) void attn_mfma(
    const u16* __restrict__ q, const u16* __restrict__ k,
    const u16* __restrict__ cont, const u16* __restrict__ embR,
    const u16* __restrict__ embT, u16* __restrict__ outp)
{
    __shared__ u16 wls[2][16][WST];
    __shared__ u16 wbs[2][16][WBST];
    __shared__ u16 bss[2][16][BST];
    const int tid = threadIdx.x;
    const int wv = tid >> 6, lane = tid & 63;
    const int l15 = lane & 15, kg8 = (lane >> 4) * 8;
    const int tt0 = (blockIdx.x * 2 + wv) * 16;
    const int bh = blockIdx.y, b = bh >> 2, h = bh & 3;
    u16* wl = &wls[wv][0][0];
    u16* wb = &wbs[wv][0][0];
    u16* bs = &bss[wv][0][0];

    // hoisted cold-miss loads: q frag + 9 K frag pairs in flight together
    const u16* qp = q + (size_t)(b * 1536 + tt0 + l15) * 256 + h * 64 + kg8;
    const bf16x8 a0 = ld8(qp);
    const bf16x8 a1 = ld8(qp + 32);
    bf16x8 k0r[9], k1r[9];
    #pragma unroll
    for (int nf = 0; nf < 9; ++nf) {
        int s = tt0 - 64 + nf * 16 + l15;
        int sc = s < 0 ? 0 : (s > 1535 ? 1535 : s);
        const u16* kp = k + (size_t)(b * 1536 + sc) * 256 + h * 64 + kg8;
        k0r[nf] = ld8(kp);
        k1r[nf] = ld8(kp + 32);
    }

    for (int i = lane; i < 16 * 8; i += 64) {
        const int t = i >> 3, c = 144 + ((i & 7) << 1);
        *reinterpret_cast<u32*>(&wl[t * WST + c]) = 0;
    }
    for (int i = lane; i < 16 * 27; i += 64) {
        const int t = i / 27, j = 101 + (i - t * 27);
        wb[t * WBST + j] = 0;
    }

    const f32x4 zf = {0.f, 0.f, 0.f, 0.f};
    f32x4 dacc[9];
    f32x4 eacc[7];
    #pragma unroll
    for (int i = 0; i < 9; ++i) dacc[i] = zf;
    #pragma unroll
    for (int i = 0; i < 7; ++i) eacc[i] = zf;

    #pragma unroll
    for (int nf = 0; nf < 9; ++nf) {
        dacc[nf] = MFMA16(a0, k0r[nf], dacc[nf], 0, 0, 0);
        dacc[nf] = MFMA16(a1, k1r[nf], dacc[nf], 0, 0, 0);
    }
    #pragma unroll
    for (int jf = 0; jf < 7; ++jf) {
        const u16* ep = embR + (jf * 16 + l15) * 64 + kg8;
        eacc[jf] = MFMA16(a0, ld8(ep), eacc[jf], 0, 0, 0);
        eacc[jf] = MFMA16(a1, ld8(ep + 32), eacc[jf], 0, 0, 0);
    }
    #pragma unroll
    for (int jf = 0; jf < 7; ++jf)
        #pragma unroll
        for (int r = 0; r < 4; ++r) {
            const int t = (lane >> 4) * 4 + r;
            bs[t * BST + jf * 16 + l15] = f2bf(eacc[jf][r]);
        }
    #pragma unroll
    for (int nf = 0; nf < 9; ++nf)
        #pragma unroll
        for (int r = 0; r < 4; ++r) {
            const int t = (lane >> 4) * 4 + r;
            const int cs = nf * 16 + l15;
            const int j = cs - t - 14;
            const int s = tt0 - 64 + cs;
            float v = dacc[nf][r];
            if (j >= 0 && j < 101 && s >= 0 && s < 1536)
                v += bf2f(bs[t * BST + j]);
            else
                v = -1e30f;
            dacc[nf][r] = v;
        }
    float inv[4];
    #pragma unroll
    for (int r = 0; r < 4; ++r) {
        float m = dacc[0][r];
        #pragma unroll
        for (int nf = 1; nf < 9; ++nf) m = fmaxf(m, dacc[nf][r]);
        m = fmaxf(m, __shfl_xor(m, 1));
        m = fmaxf(m, __shfl_xor(m, 2));
        m = fmaxf(m, __shfl_xor(m, 4));
        m = fmaxf(m, __shfl_xor(m, 8));
        float ss = 0.f;
        #pragma unroll
        for (int nf = 0; nf < 9; ++nf) {
            float e = __expf(dacc[nf][r] - m);
            dacc[nf][r] = e;
            ss += e;
        }
        ss += __shfl_xor(ss, 1);
        ss += __shfl_xor(ss, 2);
        ss += __shfl_xor(ss, 4);
        ss += __shfl_xor(ss, 8);
        inv[r] = 1.f / ss;
    }
    #pragma unroll
    for (int nf = 0; nf < 9; ++nf)
        #pragma unroll
        for (int r = 0; r < 4; ++r) {
            const int t = (lane >> 4) * 4 + r;
            const int cs = nf * 16 + l15;
            const u16 w16 = f2bf(dacc[nf][r] * inv[r]);
            wl[t * WST + cs] = w16;
            const int j = cs - t - 14;
            if (j >= 0 && j < 101) wb[t * WBST + j] = w16;
        }

    f32x4 oacc[4];
    #pragma unroll
    for (int i = 0; i < 4; ++i) oacc[i] = zf;
    #pragma unroll
    for (int kf = 0; kf < 5; ++kf) {
        const bf16x8 aw = ld8(&wl[l15 * WST + kf * 32 + kg8]);
        int sb = tt0 - 64 + kf * 32 + kg8;
        int sbc = sb < 0 ? 0 : (sb > 1528 ? 1528 : sb);
        #pragma unroll
        for (int nf = 0; nf < 4; ++nf) {
            const u16* cp = cont + (size_t)(b * 256 + h * 64 + nf * 16 + l15) * 1536 + sbc;
            oacc[nf] = MFMA16(aw, ld8(cp), oacc[nf], 0, 0, 0);
        }
    }
    #pragma unroll
    for (int kf = 0; kf < 4; ++kf) {
        const bf16x8 ab = ld8(&wb[l15 * WBST + kf * 32 + kg8]);
        #pragma unroll
        for (int nf = 0; nf < 4; ++nf) {
            const u16* ep = embT + (nf * 16 + l15) * 128 + kf * 32 + kg8;
            oacc[nf] = MFMA16(ab, ld8(ep), oacc[nf], 0, 0, 0);
        }
    }
    #pragma unroll
    for (int nf = 0; nf < 4; ++nf)
        #pragma unroll
        for (int r = 0; r < 4; ++r) {
            const int t = (lane >> 4) * 4 + r;
            outp[(size_t)(b * 1536 + tt0 + t) * 256 + h * 64 + nf * 16 + l15] =
                f2bf(oacc[nf][r]);
        }
}

// ---------------------------------------------------------------------------
// BatchNorm(train) + ReLU + scale; u32-paired bf16 loads, float2 stores.
// ---------------------------------------------------------------------------
__global__ __launch_bounds__(256) void bn_apply(
    const u16* __restrict__ pre, const float* __restrict__ gamma,
    const float* __restrict__ beta, const float* __restrict__ scale,
    float* __restrict__ out)
{
    const int o = blockIdx.x;
    const int tid = threadIdx.x;
    float v[12];
    float sum = 0.f, sumsq = 0.f;
    #pragma unroll
    for (int g = 0; g < 6; ++g) {
        const int b = (g >= 3);
        const int l = (g - 3 * b) * 512 + tid * 2;
        const u32 w = *reinterpret_cast<const u32*>(&pre[(size_t)(b * 256 + o) * 1536 + l]);
        const float v0 = __uint_as_float(w << 16);
        const float v1 = __uint_as_float(w & 0xffff0000u);
        v[g * 2] = v0; v[g * 2 + 1] = v1;
        sum += v0 + v1;
        sumsq = fmaf(v0, v0, sumsq);
        sumsq = fmaf(v1, v1, sumsq);
    }
    #pragma unroll
    for (int off = 1; off < 64; off <<= 1) {
        sum += __shfl_xor(sum, off);
        sumsq += __shfl_xor(sumsq, off);
    }
    __shared__ float rs[4], rq[4];
    const int wave = tid >> 6;
    if ((tid & 63) == 0) { rs[wave] = sum; rq[wave] = sumsq; }
    __syncthreads();
    sum = rs[0] + rs[1] + rs[2] + rs[3];
    sumsq = rq[0] + rq[1] + rq[2] + rq[3];
    const float mean = sum * (1.f / 3072.f);
    const float var = sumsq * (1.f / 3072.f) - mean * mean;
    const float is = rsqrtf(var + 1e-5f);
    const float gm = gamma[o] * is;
    const float b2 = beta[o] - mean * gm;
    const float sc = scale[o];
    #pragma unroll
    for (int g = 0; g < 6; ++g) {
        const int b = (g >= 3);
        const int l = (g - 3 * b) * 512 + tid * 2;
        float2 o2;
        o2.x = fmaxf(fmaf(v[g * 2], gm, b2), 0.f) * sc;
        o2.y = fmaxf(fmaf(v[g * 2 + 1], gm, b2), 0.f) * sc;
        *reinterpret_cast<float2*>(&out[(size_t)(b * 256 + o) * 1536 + l]) = o2;
    }
}

extern "C" void kernel_launch(void* const* d_in, const int* in_sizes, int n_in,
                              void* d_out, int out_size, void* d_ws, size_t ws_size,
                              hipStream_t stream) {
    const float* x     = (const float*)d_in[0];
    const float* Wc    = (const float*)d_in[1];
    const float* bc    = (const float*)d_in[2];
    const float* Wq    = (const float*)d_in[3];
    const float* bq    = (const float*)d_in[4];
    const float* Wk    = (const float*)d_in[5];
    const float* bk    = (const float*)d_in[6];
    const float* emb   = (const float*)d_in[7];
    const float* Wf    = (const float*)d_in[8];
    const float* bf    = (const float*)d_in[9];
    const float* gamma = (const float*)d_in[10];
    const float* beta  = (const float*)d_in[11];
    const float* scale = (const float*)d_in[12];
    float* out = (float*)d_out;
    u16* ws = (u16*)d_ws;

    const size_t NLC = 786432;  // B*C*L
    u16* xT   = ws;                 // [2][1536][256]
    u16* qb   = ws + NLC;           // [2][1536][256]
    u16* kb   = ws + 2 * NLC;       // [2][1536][256]
    u16* cbuf = ws + 3 * NLC;       // [2][256][1536]
    u16* abuf = ws + 4 * NLC;       // [2][1536][256]
    u16* pbuf = ws + 5 * NLC;       // [2][256][1536]
    u16* wcb  = ws + 6 * NLC;       // [256][256]
    u16* wqb  = wcb + 65536;
    u16* wkb  = wqb + 65536;
    u16* wfb  = wkb + 65536;
    u16* embR = wfb + 65536;        // [112][64]
    u16* embT = embR + 112 * 64;    // [64][128]

    prep<<<dim3(24, 4, 3), 256, 0, stream>>>(x, Wc, Wq, Wk, Wf, emb,
                                             xT, wcb, wqb, wkb, wfb, embR, embT);
    gemm_qkc<<<dim3(24, 8, 6), 128, 0, stream>>>(xT, wqb, bq, wkb, bk, wcb, bc,
                                                 qb, kb, cbuf);
    attn_mfma<<<dim3(48, 8), 128, 0, stream>>>(qb, kb, cbuf, embR, embT, abuf);
    gemm_f<<<dim3(24, 8, 2), 128, 0, stream>>>(wfb, bf, abuf, pbuf);
    bn_apply<<<256, 256, 0, stream>>>(pbuf, gamma, beta, scale, out);
}